// Round 18
// baseline (91.097 us; speedup 1.0000x reference)
//
#include <hip/hip_runtime.h>
#include <hip/hip_fp16.h>
#include <math.h>

// DyDCNv2: B=8, C=256, O=256, H=W=64, 3x3 modulated deformable conv + GN16
#define BB 8
#define CC 256
#define OO 256
#define HH 64
#define WW 64
#define KK 9
#define HWSZ 4096
#define CKSZ 2304
#define NG 16
#define OPG 16
#define EPSV 1e-5f

typedef _Float16 f16;
typedef f16 f16x8 __attribute__((ext_vector_type(8)));
typedef float f32x4 __attribute__((ext_vector_type(4)));

#define XH_ELEMS ((size_t)BB*HWSZ*CC)    // 8,388,608 halves (16.8 MB)
#define WF_ELEMS ((size_t)OO*CKSZ)       //   589,824 halves (1.2 MB)
#define CV_ELEMS ((size_t)BB*OO*HWSZ)    // 8,388,608 halves (16.8 MB)
#define NSTRIP 32                        // 128-position strips per image

// ---- x[b][c][hw] fp32  ->  xh[b][hw][c] f16 (channel-contiguous for gathers)
__global__ __launch_bounds__(256) void x_transpose_k(
    const float* __restrict__ x, __half* __restrict__ xh)
{
  int blk = blockIdx.x;
  int b = blk >> 8; int rem = blk & 255;
  int c0 = (rem >> 6) * 64; int hw0 = (rem & 63) * 64;
  __shared__ float st[64][65];
  int t = threadIdx.x;
  #pragma unroll
  for (int i = 0; i < 16; ++i) {
    int idx = t + i*256; int c = idx >> 6, w = idx & 63;
    st[c][w] = x[((size_t)(b*CC + c0 + c))*HWSZ + hw0 + w];
  }
  __syncthreads();
  #pragma unroll
  for (int i = 0; i < 8; ++i) {
    int idx = t + i*256; int r = idx >> 5, cp = idx & 31;
    __half2 v = __floats2half2_rn(st[cp*2][r], st[cp*2+1][r]);
    *(__half2*)&xh[((size_t)(b*HWSZ) + hw0 + r)*CC + c0 + cp*2] = v;
  }
}

// ---- weight[o][c][3][3] fp32 -> fragment-ordered f16:
// wf[cc=k*4+c0i][wm][ks][mi][lane][e]; o=wm*64+mi*16+(lane&15),
// c=c0i*64+ks*32+(lane>>4)*8+e. Each (cc,wm,ks,mi): 64 lanes x 16B coalesced.
__global__ __launch_bounds__(256) void w_frag_k(
    const float* __restrict__ w, __half* __restrict__ wf)
{
  int i = blockIdx.x*256 + threadIdx.x;   // < 589824
  int e = i & 7, lane = (i >> 3) & 63, mi = (i >> 9) & 3;
  int ks = (i >> 11) & 1, wm = (i >> 12) & 3, cc = i >> 14;
  int k = cc >> 2, c0i = cc & 3;
  int o = wm*64 + mi*16 + (lane & 15);
  int c = c0i*64 + ks*32 + (lane >> 4)*8 + e;
  wf[i] = __float2half(w[(o*CC + c)*KK + k]);
}

// ---- fused deformable-conv GEMM, one block per (b, 2-row strip) ----
// R18: 1024 thr = 16 waves in a 2-D 8o x 2p grid; block tile 256o x 128p;
// wave tile 32o x 64p (wo = wid&7 owns o in [wo*32,+32), wp = wid>>3 owns
// p-half [wp*64,+64)). Halves LDS B-reads vs R17 (each wave reads only its
// 64 rows: 128 ds_read_b128/chunk ~ 1730cy) at the cost of 2x A-requests
// (1024 lines; total VMEM ~ 2050cy) — balances the two pipes (R17 was
// LDS-saturated at ~3650cy; R12 showed VMEM ~ 1 line/cy).
// 4-deep sV ring, one __syncthreads per 2 chunks (18 barriers — R15).
// Taps in registers at k-changes (R16). A prefetched a chunk ahead (R13).
// Epilogue: f16 conv out + GN partials (group wo*2+mi; p-halves combined
// via 256B LDS + one barrier).
// NOTE: VGPR cap below the accumulator spills catastrophically (R4/R8);
// acc is 32 regs, cap 128 at (1024,4).
template<int F16OUT>
__global__ __launch_bounds__(1024, 4) void dcn_mfma_k(
    const float* __restrict__ off, const float* __restrict__ msk,
    const __half* __restrict__ xh, const __half* __restrict__ wf,
    float* __restrict__ out32, __half* __restrict__ conv16,
    float* __restrict__ psum)
{
  __shared__ __half sVl[4][128*64];      // 65536 B (4-deep ring)
  __shared__ float  sRedG[8][2][2][2];   //   256 B (GN p-half combine)

  const int t = threadIdx.x;
  const int b = blockIdx.x & 7;          // XCD-pin: one batch per XCD
  const int strip = blockIdx.x >> 3;     // 0..31 (two image rows each)
  const int h0 = strip * 2;

  const int lane = t & 63, wid = t >> 6;     // 16 waves
  const int wo = wid & 7, wp = wid >> 3;     // o-tile of 32, p-half of 64
  const int lr = lane & 15, lh = lane >> 4;
  const int gp = t >> 3, goct = t & 7;       // gather: p (0..127), oct (0..7)

  // A-frag loader: 4 coalesced 16B loads (2ks x 2mi); o-lines distinct per
  // wo, duplicated across the 2 p-halves (accounted in the line budget).
  auto load_A = [&](int cc, f16x8 a[2][2]) {
    #pragma unroll
    for (int ks = 0; ks < 2; ++ks)
      #pragma unroll
      for (int mi = 0; mi < 2; ++mi) {
        int omi = wo*2 + mi;               // 16-row o-group 0..15
        const __half* ap = wf + (size_t)(cc*4 + (omi >> 2))*4096
                              + (size_t)(ks*4 + (omi & 3))*512 + lane*8;
        a[ks][mi] = *(const f16x8*)ap;
      }
  };

  // ---- issue chunk-0/1 A-loads FIRST (latency hides under tap compute) ----
  f16x8 aregA[2][2], aregB[2][2];
  load_A(0, aregA);
  load_A(1, aregB);

  f32x4 acc[2][4];
  #pragma unroll
  for (int mi = 0; mi < 2; ++mi)
    #pragma unroll
    for (int ni = 0; ni < 4; ++ni) acc[mi][ni] = (f32x4){0.f,0.f,0.f,0.f};

  const char* xbase = (const char*)xh + (size_t)b * (HWSZ*CC*2);

  // gather-tap regs for this thread's position gp at kernel point k.
  // (8 threads share gp -> their off/msk loads are same-address broadcasts)
  uint toff[4]; __half2 twv[4];
  auto compute_taps = [&](int k) {
    int h = h0 + (gp >> 6), w = gp & 63;
    float dy = off[(((b*18) + 2*k    )*HH + h)*WW + w];
    float dx = off[(((b*18) + 2*k + 1)*HH + h)*WW + w];
    float m  = msk[(((b*KK) + k)*HH + h)*WW + w];
    float py = (float)(h + (k/3) - 1) + dy;
    float px = (float)(w + (k%3) - 1) + dx;
    float y0f = floorf(py), x0f = floorf(px);
    float wy = py - y0f, wx = px - x0f;
    int y0 = (int)y0f, x0 = (int)x0f;
    #pragma unroll
    for (int tap = 0; tap < 4; ++tap) {
      int yy = y0 + (tap >> 1), xx = x0 + (tap & 1);
      bool v = (yy >= 0) & (yy < HH) & (xx >= 0) & (xx < WW);
      float bw = ((tap >> 1) ? wy : 1.f - wy) * ((tap & 1) ? wx : 1.f - wx);
      float wgt = v ? bw * m : 0.f;
      int cy = min(max(yy, 0), HH-1), cx = min(max(xx, 0), WW-1);
      toff[tap] = (uint)((cy*WW + cx) * (CC*2));
      twv[tap]  = __float2half2_rn(wgt);
    }
  };
  int tk = 0;
  compute_taps(0);

  auto combine_write = [&](uint4 r0, uint4 r1, uint4 r2, uint4 r3,
                           __half* dst) {
    const __half2* t0 = (const __half2*)&r0; const __half2* t1 = (const __half2*)&r1;
    const __half2* t2 = (const __half2*)&r2; const __half2* t3 = (const __half2*)&r3;
    __half2 o_[4];
    #pragma unroll
    for (int r = 0; r < 4; ++r)
      o_[r] = __hfma2(twv[0], t0[r], __hfma2(twv[1], t1[r],
              __hfma2(twv[2], t2[r], __hmul2(twv[3], t3[r]))));
    *(uint4*)&dst[gp*64 + ((goct ^ (gp & 7)) << 3)] = *(uint4*)o_;
  };

  // full gather of chunk cc into dst buffer (4 x 16B loads per thread)
  auto gather_chunk = [&](int cc, __half* dst) {
    int kn = cc >> 2, c0n = (cc & 3) << 6;
    if (kn != tk) { compute_taps(kn); tk = kn; }
    const char* cb = xbase + (size_t)(c0n*2) + goct*16;
    uint4 r0 = *(const uint4*)(cb + toff[0]);
    uint4 r1 = *(const uint4*)(cb + toff[1]);
    uint4 r2 = *(const uint4*)(cb + toff[2]);
    uint4 r3 = *(const uint4*)(cb + toff[3]);
    combine_write(r0, r1, r2, r3, dst);
  };

  // ---- prologue gathers: chunk 0 -> buf0, chunk 1 -> buf1 ----
  gather_chunk(0, sVl[0]);
  gather_chunk(1, sVl[1]);

  // half-pair: prefetch-issue G(ccf), MFMA(ccm), combine G(ccf), reload A(ccf)
  auto do_half = [&](int ccm, int ccf, f16x8 aCur[2][2]) {
    bool pf = (ccf < 36);
    int kn = ccf >> 2, c0n = (ccf & 3) << 6;
    uint4 g0, g1, g2, g3;
    if (pf) {
      if (kn != tk) { compute_taps(kn); tk = kn; }
      const char* cb = xbase + (size_t)(c0n*2) + goct*16;
      g0 = *(const uint4*)(cb + toff[0]);
      g1 = *(const uint4*)(cb + toff[1]);
      g2 = *(const uint4*)(cb + toff[2]);
      g3 = *(const uint4*)(cb + toff[3]);
    }

    // ---- MFMA(ccm): B-frags = this wave's 64-row p-half only ----
    const __half* vb = sVl[ccm & 3];
    #pragma unroll
    for (int ks = 0; ks < 2; ++ks) {
      f16x8 brg[4];
      #pragma unroll
      for (int ni = 0; ni < 4; ++ni) {
        int r = wp*64 + ni*16 + lr;
        brg[ni] = *(const f16x8*)&vb[r*64 + (((ks*4 + lh) ^ (r & 7)) << 3)];
      }
      #pragma unroll
      for (int mi = 0; mi < 2; ++mi)
        #pragma unroll
        for (int ni = 0; ni < 4; ++ni)
          acc[mi][ni] = __builtin_amdgcn_mfma_f32_16x16x32_f16(
              aCur[ks][mi], brg[ni], acc[mi][ni], 0, 0, 0);
    }

    if (pf) {
      combine_write(g0, g1, g2, g3, sVl[ccf & 3]);
      load_A(ccf, aCur);     // resolves during the next MFMA phase(s)
    }
  };

  #pragma unroll 1
  for (int ccp = 0; ccp < 36; ccp += 2) {   // 18 barriers total
    __syncthreads();   // bufs[ccp&3],[(ccp+1)&3] ready; write targets free
    do_half(ccp,     ccp + 2, aregA);
    do_half(ccp + 1, ccp + 3, aregB);
  }

  // ---- epilogue 1: conv output (positions strip*128 + p, contiguous) ----
  #pragma unroll
  for (int mi = 0; mi < 2; ++mi) {
    #pragma unroll
    for (int ni = 0; ni < 4; ++ni) {
      int o  = wo*32 + mi*16 + lh*4;
      int pp = wp*64 + ni*16 + lr;
      #pragma unroll
      for (int j = 0; j < 4; ++j) {
        size_t idx = ((size_t)(b*OO + o + j))*HWSZ + strip*128 + pp;
        if (F16OUT) conv16[idx] = __float2half(acc[mi][ni][j]);
        else        out32[idx] = acc[mi][ni][j];
      }
    }
  }

  // ---- epilogue 2: fused GN partials. Group g = wo*2+mi; combine the two
  //      p-halves (wp) via 256B LDS. ----
  if (F16OUT) {
    #pragma unroll
    for (int mi = 0; mi < 2; ++mi) {
      float s1 = 0.f, s2 = 0.f;
      #pragma unroll
      for (int ni = 0; ni < 4; ++ni)
        #pragma unroll
        for (int j = 0; j < 4; ++j) {
          float v = acc[mi][ni][j];
          s1 += v; s2 += v*v;
        }
      #pragma unroll
      for (int d = 32; d > 0; d >>= 1) {
        s1 += __shfl_xor(s1, d);
        s2 += __shfl_xor(s2, d);
      }
      if (lane == 0) {
        sRedG[wo][mi][wp][0] = s1;
        sRedG[wo][mi][wp][1] = s2;
      }
    }
    __syncthreads();
    if (t < 16) {    // group g = t: wo = g>>1, mi = g&1
      float s1 = sRedG[t >> 1][t & 1][0][0] + sRedG[t >> 1][t & 1][1][0];
      float s2 = sRedG[t >> 1][t & 1][0][1] + sRedG[t >> 1][t & 1][1][1];
      psum[(size_t)blockIdx.x*32 + t*2]     = s1;
      psum[(size_t)blockIdx.x*32 + t*2 + 1] = s2;
    }
  }
}

// ---- GN finalize: sum psum over strips, normalize f16 conv -> f32 out ----
__global__ __launch_bounds__(256) void gn_norm2_k(
    const __half* __restrict__ conv16, const float* __restrict__ psum,
    const float* __restrict__ gamma, const float* __restrict__ beta,
    float* __restrict__ out)
{
  int bid = blockIdx.x;            // 4096
  int bo = bid >> 1;
  int b = bo >> 8, o = bo & 255;
  int g = o >> 4;
  float s1 = 0.f, s2 = 0.f;
  for (int st = 0; st < NSTRIP; ++st) {
    // writer block id = strip*8 + b  (R10 bug: transposed index)
    s1 += psum[(size_t)(st*8 + b)*32 + g*2];
    s2 += psum[(size_t)(st*8 + b)*32 + g*2 + 1];
  }
  const float invN = 1.f / (float)(OPG*HWSZ);
  float mean = s1 * invN;
  float var  = s2 * invN - mean*mean;
  float inv = rsqrtf(var + EPSV);
  float sc = gamma[o]*inv;
  float sh = beta[o] - mean*sc;

  size_t e0 = ((size_t)(b*OO + o))*HWSZ + (size_t)(bid & 1)*2048
            + (size_t)threadIdx.x*8;
  uint4 u = *(const uint4*)(conv16 + e0);
  const __half2* hh = (const __half2*)&u;
  float r[8];
  #pragma unroll
  for (int j = 0; j < 4; ++j) {
    float2 f = __half22float2(hh[j]);
    r[2*j] = f.x; r[2*j+1] = f.y;
  }
  *(float4*)&out[e0]     = make_float4(r[0]*sc+sh, r[1]*sc+sh, r[2]*sc+sh, r[3]*sc+sh);
  *(float4*)&out[e0 + 4] = make_float4(r[4]*sc+sh, r[5]*sc+sh, r[6]*sc+sh, r[7]*sc+sh);
}

// ---- fallback GN (f32 in-place) ----
__global__ __launch_bounds__(1024) void gn_stats_k(
    const float* __restrict__ out, float* __restrict__ stats)
{
  int bg = blockIdx.x;
  const float4* p = (const float4*)(out + (size_t)bg*OPG*HWSZ);
  const int n4 = OPG*HWSZ/4;
  float s1 = 0.f, s2 = 0.f;
  for (int i = threadIdx.x; i < n4; i += 1024) {
    float4 v = p[i];
    s1 += v.x + v.y + v.z + v.w;
    s2 += v.x*v.x + v.y*v.y + v.z*v.z + v.w*v.w;
  }
  #pragma unroll
  for (int o2 = 32; o2 > 0; o2 >>= 1) {
    s1 += __shfl_down(s1, o2);
    s2 += __shfl_down(s2, o2);
  }
  __shared__ float r1[16], r2[16];
  int wd = threadIdx.x >> 6, lane = threadIdx.x & 63;
  if (lane == 0) { r1[wd] = s1; r2[wd] = s2; }
  __syncthreads();
  if (threadIdx.x == 0) {
    float t1 = 0.f, t2 = 0.f;
    #pragma unroll
    for (int i = 0; i < 16; i++) { t1 += r1[i]; t2 += r2[i]; }
    const float invN = 1.f / (float)(OPG*HWSZ);
    float mean = t1 * invN;
    float var  = t2 * invN - mean*mean;
    stats[bg*2]   = mean;
    stats[bg*2+1] = var;
  }
}

__global__ __launch_bounds__(256) void gn_norm_k(
    float* __restrict__ out, const float* __restrict__ stats,
    const float* __restrict__ gamma, const float* __restrict__ beta)
{
  size_t i = (size_t)blockIdx.x*256 + threadIdx.x;
  const size_t n4 = (size_t)BB*OO*HWSZ/4;
  if (i >= n4) return;
  size_t base = i*4;
  int bo = (int)(base / HWSZ);
  int b = bo / OO, o = bo - b*OO;
  int g = o >> 4;
  float mean = stats[(b*NG+g)*2], var = stats[(b*NG+g)*2+1];
  float inv = rsqrtf(var + EPSV);
  float sc = gamma[o]*inv;
  float sh = beta[o] - mean*sc;
  float4 v = *(float4*)&out[base];
  v.x = v.x*sc + sh; v.y = v.y*sc + sh;
  v.z = v.z*sc + sh; v.w = v.w*sc + sh;
  *(float4*)&out[base] = v;
}

extern "C" void kernel_launch(void* const* d_in, const int* in_sizes, int n_in,
                              void* d_out, int out_size, void* d_ws, size_t ws_size,
                              hipStream_t stream) {
  const float* x      = (const float*)d_in[0];
  const float* offset = (const float*)d_in[1];
  const float* mask   = (const float*)d_in[2];
  const float* weight = (const float*)d_in[3];
  const float* gamma  = (const float*)d_in[4];
  const float* beta   = (const float*)d_in[5];
  float* out = (float*)d_out;

  __half* xh   = (__half*)d_ws;
  __half* wf   = xh + XH_ELEMS;
  __half* cv   = wf + WF_ELEMS;
  float* psum  = (float*)(cv + CV_ELEMS);

  const size_t need = (XH_ELEMS + WF_ELEMS + CV_ELEMS)*2
                    + (size_t)BB*NSTRIP*32*4 + 1024;

  x_transpose_k<<<BB*4*64, 256, 0, stream>>>(x, xh);
  w_frag_k<<<(int)(WF_ELEMS/256), 256, 0, stream>>>(weight, wf);

  if (ws_size >= need) {
    dcn_mfma_k<1><<<BB*NSTRIP, 1024, 0, stream>>>(offset, mask, xh, wf,
                                                  (float*)nullptr, cv, psum);
    gn_norm2_k<<<4096, 256, 0, stream>>>(cv, psum, gamma, beta, out);
  } else {
    float* stats = (float*)(wf + WF_ELEMS);
    dcn_mfma_k<0><<<BB*NSTRIP, 1024, 0, stream>>>(offset, mask, xh, wf,
                                                  out, (__half*)nullptr,
                                                  (float*)nullptr);
    gn_stats_k<<<BB*NG, 1024, 0, stream>>>(out, stats);
    gn_norm_k<<<(int)((size_t)BB*OO*HWSZ/4 + 255)/256, 256, 0, stream>>>(
        out, stats, gamma, beta);
  }
}

// Round 19
// 79.970 us; speedup vs baseline: 1.1391x; 1.1391x over previous
//
#include <hip/hip_runtime.h>
#include <hip/hip_fp16.h>
#include <math.h>

// DyDCNv2: B=8, C=256, O=256, H=W=64, 3x3 modulated deformable conv + GN16
// FINAL structure (R16 optimum, reverted after R17/R18 regressions):
//  - fp16 MFMA GEMM over im2col'd deformable samples, 256o x 128p blocks
//  - 8 waves, wave tile 32o x 128p (all A-frag lines distinct across waves)
//  - 4-deep sV LDS ring, one barrier per 2 chunks (18 barriers)
//  - bilinear taps computed in registers at k-changes
//  - A-frags direct from L2-resident fragment-ordered wf, prefetched 1 ahead
//  - fused GN partial sums in epilogue; light finalize kernel
#define BB 8
#define CC 256
#define OO 256
#define HH 64
#define WW 64
#define KK 9
#define HWSZ 4096
#define CKSZ 2304
#define NG 16
#define OPG 16
#define EPSV 1e-5f

typedef _Float16 f16;
typedef f16 f16x8 __attribute__((ext_vector_type(8)));
typedef float f32x4 __attribute__((ext_vector_type(4)));

#define XH_ELEMS ((size_t)BB*HWSZ*CC)    // 8,388,608 halves (16.8 MB)
#define WF_ELEMS ((size_t)OO*CKSZ)       //   589,824 halves (1.2 MB)
#define CV_ELEMS ((size_t)BB*OO*HWSZ)    // 8,388,608 halves (16.8 MB)
#define NSTRIP 32                        // 128-position strips per image

// ---- x[b][c][hw] fp32  ->  xh[b][hw][c] f16 (channel-contiguous for gathers)
__global__ __launch_bounds__(256) void x_transpose_k(
    const float* __restrict__ x, __half* __restrict__ xh)
{
  int blk = blockIdx.x;
  int b = blk >> 8; int rem = blk & 255;
  int c0 = (rem >> 6) * 64; int hw0 = (rem & 63) * 64;
  __shared__ float st[64][65];
  int t = threadIdx.x;
  #pragma unroll
  for (int i = 0; i < 16; ++i) {
    int idx = t + i*256; int c = idx >> 6, w = idx & 63;
    st[c][w] = x[((size_t)(b*CC + c0 + c))*HWSZ + hw0 + w];
  }
  __syncthreads();
  #pragma unroll
  for (int i = 0; i < 8; ++i) {
    int idx = t + i*256; int r = idx >> 5, cp = idx & 31;
    __half2 v = __floats2half2_rn(st[cp*2][r], st[cp*2+1][r]);
    *(__half2*)&xh[((size_t)(b*HWSZ) + hw0 + r)*CC + c0 + cp*2] = v;
  }
}

// ---- weight[o][c][3][3] fp32 -> fragment-ordered f16:
// wf[cc=k*4+c0i][wm][ks][mi][lane][e]; o=wm*64+mi*16+(lane&15),
// c=c0i*64+ks*32+(lane>>4)*8+e. Each (cc,wm,ks,mi): 64 lanes x 16B coalesced.
__global__ __launch_bounds__(256) void w_frag_k(
    const float* __restrict__ w, __half* __restrict__ wf)
{
  int i = blockIdx.x*256 + threadIdx.x;   // < 589824
  int e = i & 7, lane = (i >> 3) & 63, mi = (i >> 9) & 3;
  int ks = (i >> 11) & 1, wm = (i >> 12) & 3, cc = i >> 14;
  int k = cc >> 2, c0i = cc & 3;
  int o = wm*64 + mi*16 + (lane & 15);
  int c = c0i*64 + ks*32 + (lane >> 4)*8 + e;
  wf[i] = __float2half(w[(o*CC + c)*KK + k]);
}

// ---- fused deformable-conv GEMM, one block per (b, 2-row strip) ----
// 512 thr = 8 waves; block tile 256o x 128p; wave tile 32o x 128p.
template<int F16OUT>
__global__ __launch_bounds__(512, 2) void dcn_mfma_k(
    const float* __restrict__ off, const float* __restrict__ msk,
    const __half* __restrict__ xh, const __half* __restrict__ wf,
    float* __restrict__ out32, __half* __restrict__ conv16,
    float* __restrict__ psum)
{
  __shared__ __half sVl[4][128*64];      // 65536 B (4-deep ring; whole LDS)

  const int t = threadIdx.x;
  const int b = blockIdx.x & 7;          // XCD-pin: one batch per XCD
  const int strip = blockIdx.x >> 3;     // 0..31 (two image rows each)
  const int h0 = strip * 2;

  const int lane = t & 63, wid = t >> 6;     // wid = o-tile of 32
  const int lr = lane & 15, lh = lane >> 4;
  const int gp = t >> 2, gq = t & 3;         // gather: p (0..127), octets {gq,gq+4}

  // A-frag loader: 4 coalesced 16B loads, all lines distinct across waves
  auto load_A = [&](int cc, f16x8 a[2][2]) {
    #pragma unroll
    for (int ks = 0; ks < 2; ++ks)
      #pragma unroll
      for (int mi = 0; mi < 2; ++mi) {
        int omi = wid*2 + mi;              // 16-row o-group 0..15
        const __half* ap = wf + (size_t)(cc*4 + (omi >> 2))*4096
                              + (size_t)(ks*4 + (omi & 3))*512 + lane*8;
        a[ks][mi] = *(const f16x8*)ap;
      }
  };

  // ---- issue chunk-0/1 A-loads FIRST (latency hides under tap compute) ----
  f16x8 aregA[2][2], aregB[2][2];
  load_A(0, aregA);
  load_A(1, aregB);

  f32x4 acc[2][8];
  #pragma unroll
  for (int mi = 0; mi < 2; ++mi)
    #pragma unroll
    for (int ni = 0; ni < 8; ++ni) acc[mi][ni] = (f32x4){0.f,0.f,0.f,0.f};

  const char* xbase = (const char*)xh + (size_t)b * (HWSZ*CC*2);

  // gather-tap regs for this thread's own position gp at kernel point k.
  // (4 threads share gp -> their off/msk loads are same-address broadcasts)
  uint toff[4]; __half2 twv[4];
  auto compute_taps = [&](int k) {
    int h = h0 + (gp >> 6), w = gp & 63;
    float dy = off[(((b*18) + 2*k    )*HH + h)*WW + w];
    float dx = off[(((b*18) + 2*k + 1)*HH + h)*WW + w];
    float m  = msk[(((b*KK) + k)*HH + h)*WW + w];
    float py = (float)(h + (k/3) - 1) + dy;
    float px = (float)(w + (k%3) - 1) + dx;
    float y0f = floorf(py), x0f = floorf(px);
    float wy = py - y0f, wx = px - x0f;
    int y0 = (int)y0f, x0 = (int)x0f;
    #pragma unroll
    for (int tap = 0; tap < 4; ++tap) {
      int yy = y0 + (tap >> 1), xx = x0 + (tap & 1);
      bool v = (yy >= 0) & (yy < HH) & (xx >= 0) & (xx < WW);
      float bw = ((tap >> 1) ? wy : 1.f - wy) * ((tap & 1) ? wx : 1.f - wx);
      float wgt = v ? bw * m : 0.f;
      int cy = min(max(yy, 0), HH-1), cx = min(max(xx, 0), WW-1);
      toff[tap] = (uint)((cy*WW + cx) * (CC*2));
      twv[tap]  = __float2half2_rn(wgt);
    }
  };
  int tk = 0;
  compute_taps(0);

  auto combine_write = [&](uint4 r0, uint4 r1, uint4 r2, uint4 r3,
                           int oct, __half* dst) {
    const __half2* t0 = (const __half2*)&r0; const __half2* t1 = (const __half2*)&r1;
    const __half2* t2 = (const __half2*)&r2; const __half2* t3 = (const __half2*)&r3;
    __half2 o_[4];
    #pragma unroll
    for (int r = 0; r < 4; ++r)
      o_[r] = __hfma2(twv[0], t0[r], __hfma2(twv[1], t1[r],
              __hfma2(twv[2], t2[r], __hmul2(twv[3], t3[r]))));
    *(uint4*)&dst[gp*64 + ((oct ^ (gp & 7)) << 3)] = *(uint4*)o_;
  };

  // full gather of chunk cc into dst buffer (issues + combines)
  auto gather_chunk = [&](int cc, __half* dst) {
    int kn = cc >> 2, c0n = (cc & 3) << 6;
    if (kn != tk) { compute_taps(kn); tk = kn; }
    const char* cb = xbase + (size_t)(c0n*2) + gq*16;
    uint4 a0 = *(const uint4*)(cb + toff[0]);
    uint4 a1 = *(const uint4*)(cb + toff[1]);
    uint4 a2 = *(const uint4*)(cb + toff[2]);
    uint4 a3 = *(const uint4*)(cb + toff[3]);
    uint4 b0 = *(const uint4*)(cb + toff[0] + 64);
    uint4 b1 = *(const uint4*)(cb + toff[1] + 64);
    uint4 b2 = *(const uint4*)(cb + toff[2] + 64);
    uint4 b3 = *(const uint4*)(cb + toff[3] + 64);
    combine_write(a0, a1, a2, a3, gq,     dst);
    combine_write(b0, b1, b2, b3, gq + 4, dst);
  };

  // ---- prologue gathers: chunk 0 -> buf0, chunk 1 -> buf1 ----
  gather_chunk(0, sVl[0]);
  gather_chunk(1, sVl[1]);

  // half-pair: prefetch-issue G(ccf), MFMA(ccm), combine G(ccf), reload A(ccf)
  auto do_half = [&](int ccm, int ccf, f16x8 aCur[2][2]) {
    bool pf = (ccf < 36);
    int kn = ccf >> 2, c0n = (ccf & 3) << 6;
    uint4 ga0, ga1, ga2, ga3, gb0, gb1, gb2, gb3;
    if (pf) {
      if (kn != tk) { compute_taps(kn); tk = kn; }
      const char* cb = xbase + (size_t)(c0n*2) + gq*16;
      ga0 = *(const uint4*)(cb + toff[0]);
      ga1 = *(const uint4*)(cb + toff[1]);
      ga2 = *(const uint4*)(cb + toff[2]);
      ga3 = *(const uint4*)(cb + toff[3]);
      gb0 = *(const uint4*)(cb + toff[0] + 64);
      gb1 = *(const uint4*)(cb + toff[1] + 64);
      gb2 = *(const uint4*)(cb + toff[2] + 64);
      gb3 = *(const uint4*)(cb + toff[3] + 64);
    }

    // ---- MFMA(ccm): B-frags (all 128 rows) from sVl[ccm&3], A from regs ----
    const __half* vb = sVl[ccm & 3];
    #pragma unroll
    for (int ks = 0; ks < 2; ++ks) {
      f16x8 brg[8];
      #pragma unroll
      for (int ni = 0; ni < 8; ++ni) {
        int r = ni*16 + lr;
        brg[ni] = *(const f16x8*)&vb[r*64 + (((ks*4 + lh) ^ (r & 7)) << 3)];
      }
      #pragma unroll
      for (int mi = 0; mi < 2; ++mi)
        #pragma unroll
        for (int ni = 0; ni < 8; ++ni)
          acc[mi][ni] = __builtin_amdgcn_mfma_f32_16x16x32_f16(
              aCur[ks][mi], brg[ni], acc[mi][ni], 0, 0, 0);
    }

    if (pf) {
      __half* dst = sVl[ccf & 3];
      combine_write(ga0, ga1, ga2, ga3, gq,     dst);
      combine_write(gb0, gb1, gb2, gb3, gq + 4, dst);
      load_A(ccf, aCur);     // resolves during the next MFMA phase(s)
    }
  };

  #pragma unroll 1
  for (int ccp = 0; ccp < 36; ccp += 2) {   // 18 barriers total
    __syncthreads();   // bufs[ccp&3],[(ccp+1)&3] ready; write targets free
    do_half(ccp,     ccp + 2, aregA);
    do_half(ccp + 1, ccp + 3, aregB);
  }

  // ---- epilogue 1: conv output (positions strip*128 + p, contiguous) ----
  #pragma unroll
  for (int mi = 0; mi < 2; ++mi) {
    #pragma unroll
    for (int ni = 0; ni < 8; ++ni) {
      int ob = wid*32 + mi*16 + lh*4;
      int pp = ni*16 + lr;
      #pragma unroll
      for (int j = 0; j < 4; ++j) {
        size_t idx = ((size_t)(b*OO + ob + j))*HWSZ + strip*128 + pp;
        if (F16OUT) conv16[idx] = __float2half(acc[mi][ni][j]);
        else        out32[idx] = acc[mi][ni][j];
      }
    }
  }

  // ---- epilogue 2: fused GN partials. (wid,mi) owns EXACTLY group
  //      g = wid*2+mi (o-range [g*16, g*16+16)) -> wave-local reduce only.
  if (F16OUT) {
    #pragma unroll
    for (int mi = 0; mi < 2; ++mi) {
      float s1 = 0.f, s2 = 0.f;
      #pragma unroll
      for (int ni = 0; ni < 8; ++ni)
        #pragma unroll
        for (int j = 0; j < 4; ++j) {
          float v = acc[mi][ni][j];
          s1 += v; s2 += v*v;
        }
      #pragma unroll
      for (int d = 32; d > 0; d >>= 1) {
        s1 += __shfl_xor(s1, d);
        s2 += __shfl_xor(s2, d);
      }
      if (lane == 0) {
        int g = wid*2 + mi;
        psum[(size_t)blockIdx.x*32 + g*2]     = s1;
        psum[(size_t)blockIdx.x*32 + g*2 + 1] = s2;
      }
    }
  }
}

// ---- GN finalize: sum psum over strips, normalize f16 conv -> f32 out ----
__global__ __launch_bounds__(256) void gn_norm2_k(
    const __half* __restrict__ conv16, const float* __restrict__ psum,
    const float* __restrict__ gamma, const float* __restrict__ beta,
    float* __restrict__ out)
{
  int bid = blockIdx.x;            // 4096
  int bo = bid >> 1;
  int b = bo >> 8, o = bo & 255;
  int g = o >> 4;
  float s1 = 0.f, s2 = 0.f;
  for (int st = 0; st < NSTRIP; ++st) {
    // writer block id = strip*8 + b  (R10 bug: transposed index)
    s1 += psum[(size_t)(st*8 + b)*32 + g*2];
    s2 += psum[(size_t)(st*8 + b)*32 + g*2 + 1];
  }
  const float invN = 1.f / (float)(OPG*HWSZ);
  float mean = s1 * invN;
  float var  = s2 * invN - mean*mean;
  float inv = rsqrtf(var + EPSV);
  float sc = gamma[o]*inv;
  float sh = beta[o] - mean*sc;

  size_t e0 = ((size_t)(b*OO + o))*HWSZ + (size_t)(bid & 1)*2048
            + (size_t)threadIdx.x*8;
  uint4 u = *(const uint4*)(conv16 + e0);
  const __half2* hh = (const __half2*)&u;
  float r[8];
  #pragma unroll
  for (int j = 0; j < 4; ++j) {
    float2 f = __half22float2(hh[j]);
    r[2*j] = f.x; r[2*j+1] = f.y;
  }
  *(float4*)&out[e0]     = make_float4(r[0]*sc+sh, r[1]*sc+sh, r[2]*sc+sh, r[3]*sc+sh);
  *(float4*)&out[e0 + 4] = make_float4(r[4]*sc+sh, r[5]*sc+sh, r[6]*sc+sh, r[7]*sc+sh);
}

// ---- fallback GN (f32 in-place) ----
__global__ __launch_bounds__(1024) void gn_stats_k(
    const float* __restrict__ out, float* __restrict__ stats)
{
  int bg = blockIdx.x;
  const float4* p = (const float4*)(out + (size_t)bg*OPG*HWSZ);
  const int n4 = OPG*HWSZ/4;
  float s1 = 0.f, s2 = 0.f;
  for (int i = threadIdx.x; i < n4; i += 1024) {
    float4 v = p[i];
    s1 += v.x + v.y + v.z + v.w;
    s2 += v.x*v.x + v.y*v.y + v.z*v.z + v.w*v.w;
  }
  #pragma unroll
  for (int o2 = 32; o2 > 0; o2 >>= 1) {
    s1 += __shfl_down(s1, o2);
    s2 += __shfl_down(s2, o2);
  }
  __shared__ float r1[16], r2[16];
  int wd = threadIdx.x >> 6, lane = threadIdx.x & 63;
  if (lane == 0) { r1[wd] = s1; r2[wd] = s2; }
  __syncthreads();
  if (threadIdx.x == 0) {
    float t1 = 0.f, t2 = 0.f;
    #pragma unroll
    for (int i = 0; i < 16; i++) { t1 += r1[i]; t2 += r2[i]; }
    const float invN = 1.f / (float)(OPG*HWSZ);
    float mean = t1 * invN;
    float var  = t2 * invN - mean*mean;
    stats[bg*2]   = mean;
    stats[bg*2+1] = var;
  }
}

__global__ __launch_bounds__(256) void gn_norm_k(
    float* __restrict__ out, const float* __restrict__ stats,
    const float* __restrict__ gamma, const float* __restrict__ beta)
{
  size_t i = (size_t)blockIdx.x*256 + threadIdx.x;
  const size_t n4 = (size_t)BB*OO*HWSZ/4;
  if (i >= n4) return;
  size_t base = i*4;
  int bo = (int)(base / HWSZ);
  int b = bo / OO, o = bo - b*OO;
  int g = o >> 4;
  float mean = stats[(b*NG+g)*2], var = stats[(b*NG+g)*2+1];
  float inv = rsqrtf(var + EPSV);
  float sc = gamma[o]*inv;
  float sh = beta[o] - mean*sc;
  float4 v = *(float4*)&out[base];
  v.x = v.x*sc + sh; v.y = v.y*sc + sh;
  v.z = v.z*sc + sh; v.w = v.w*sc + sh;
  *(float4*)&out[base] = v;
}

extern "C" void kernel_launch(void* const* d_in, const int* in_sizes, int n_in,
                              void* d_out, int out_size, void* d_ws, size_t ws_size,
                              hipStream_t stream) {
  const float* x      = (const float*)d_in[0];
  const float* offset = (const float*)d_in[1];
  const float* mask   = (const float*)d_in[2];
  const float* weight = (const float*)d_in[3];
  const float* gamma  = (const float*)d_in[4];
  const float* beta   = (const float*)d_in[5];
  float* out = (float*)d_out;

  __half* xh   = (__half*)d_ws;
  __half* wf   = xh + XH_ELEMS;
  __half* cv   = wf + WF_ELEMS;
  float* psum  = (float*)(cv + CV_ELEMS);

  const size_t need = (XH_ELEMS + WF_ELEMS + CV_ELEMS)*2
                    + (size_t)BB*NSTRIP*32*4 + 1024;

  x_transpose_k<<<BB*4*64, 256, 0, stream>>>(x, xh);
  w_frag_k<<<(int)(WF_ELEMS/256), 256, 0, stream>>>(weight, wf);

  if (ws_size >= need) {
    dcn_mfma_k<1><<<BB*NSTRIP, 512, 0, stream>>>(offset, mask, xh, wf,
                                                 (float*)nullptr, cv, psum);
    gn_norm2_k<<<4096, 256, 0, stream>>>(cv, psum, gamma, beta, out);
  } else {
    float* stats = (float*)(wf + WF_ELEMS);
    dcn_mfma_k<0><<<BB*NSTRIP, 512, 0, stream>>>(offset, mask, xh, wf,
                                                 out, (__half*)nullptr,
                                                 (float*)nullptr);
    gn_stats_k<<<BB*NG, 1024, 0, stream>>>(out, stats);
    gn_norm_k<<<(int)((size_t)BB*OO*HWSZ/4 + 255)/256, 256, 0, stream>>>(
        out, stats, gamma, beta);
  }
}